// Round 8
// baseline (521.808 us; speedup 1.0000x reference)
//
#include <hip/hip_runtime.h>
#include <hip/hip_bf16.h>
#include <hip/hip_cooperative_groups.h>
#include <math.h>

namespace cg = cooperative_groups;

// MultiSimilarityLoss B=8192 D=128, sim = F·F^T via bf16 MFMA 16x16x32.
// R8: cooperative single-dispatch with 2x co-residency headroom (128-thread
// blocks: 1024 blocks needs 8/CU vs capacity 8/CU-with-margin; R7's 256-thr
// config asked for EXACTLY capacity and the launch failed silently) + checked
// return code with a phase-sliced 4-dispatch fallback of the same kernel.
// phase: -1 = all phases w/ grid.sync ; 0=cast 1=ms1 2=fold+ms2 3=fin.

#define B_N    8192
#define DDIM   128
#define NSPLIT 16               // j-splits
#define NIB    64               // i-blocks ; grid = 1024 blocks x 128 thr
#define JRANGE 512              // j per block
#define JT     16               // j rows per MFMA tile
#define NJT    32               // iterations
#define NG     4                // 16-i groups per wave (64 i per wave)

typedef __attribute__((ext_vector_type(8))) short bf16x8;  // 8 bf16 = 4 VGPRs
typedef __attribute__((ext_vector_type(4))) float f32x4;

static constexpr float ONE_EPS  = 1.0f - 1e-5f;
static constexpr float F_MARGIN = 0.1f;
// base-2 folded: exp(-2(s-.5)) = 2^(KP2A*s+KP2B) ; exp(40(s-.5)) = 2^(KN2A*s+KN2B)
static constexpr float KP2A = -2.8853900817779268f, KP2B =  1.4426950408889634f;
static constexpr float KN2A = 57.7078016355585400f, KN2B = -28.8539008177792680f;

#if __has_builtin(__builtin_amdgcn_exp2f)
#define EXP2F(x) __builtin_amdgcn_exp2f(x)
#else
#define EXP2F(x) __expf((x) * 0.6931471805599453f)
#endif

__global__ __launch_bounds__(128, 4)
void ms_all(int phase,
            const float* __restrict__ feats, const int* __restrict__ labels,
            ushort* __restrict__ fb,
            float* __restrict__ minp_part, float* __restrict__ maxn_part,
            float* __restrict__ psum_part, float* __restrict__ nsum_part,
            float* __restrict__ out)
{
    const int tid = threadIdx.x;
    const int bid = blockIdx.x;
    const bool coop = (phase < 0);

    // ---------------- phase 0: cast fp32 -> bf16 (RNE), 8 floats/thread
    if (coop || phase == 0) {
        int idx = (bid * 128 + tid) * 8;
        #pragma unroll
        for (int h = 0; h < 2; ++h) {
            float4 v = *(const float4*)(feats + idx + h * 4);
            ushort4 o; uint u;
            u = __float_as_uint(v.x); o.x = (ushort)((u + 0x7fffu + ((u >> 16) & 1u)) >> 16);
            u = __float_as_uint(v.y); o.y = (ushort)((u + 0x7fffu + ((u >> 16) & 1u)) >> 16);
            u = __float_as_uint(v.z); o.z = (ushort)((u + 0x7fffu + ((u >> 16) & 1u)) >> 16);
            u = __float_as_uint(v.w); o.w = (ushort)((u + 0x7fffu + ((u >> 16) & 1u)) >> 16);
            *(ushort4*)(fb + idx + h * 4) = o;
        }
    }
    if (coop) cg::this_grid().sync();

    const int bx  = bid & (NIB - 1);      // i-block
    const int by  = bid >> 6;             // j-split (0..15)
    const int w   = tid >> 6, lane = tid & 63;
    const int q   = lane >> 4, c = lane & 15;
    const int i0  = bx * 128, j0 = by * JRANGE;
    const int iw0 = i0 + w * 64;

    const ushort* jbase = fb + (size_t)(j0 + c) * DDIM + q * 8;
    const int*    lbase = labels + j0 + q * 4;

    // ---------------- phase 1: per-row min_pos / max_neg over this j-split
    if (coop || phase == 1) {
        bf16x8 ifr[NG][4];
        int    li[NG];
        #pragma unroll
        for (int g = 0; g < NG; ++g) {
            int row = iw0 + g * 16 + c;
            #pragma unroll
            for (int ks = 0; ks < 4; ++ks)
                ifr[g][ks] = *(const bf16x8*)(fb + row * DDIM + ks * 32 + q * 8);
            li[g] = labels[row];
        }

        float vmin[NG], vmax[NG];
        #pragma unroll
        for (int g = 0; g < NG; ++g) { vmin[g] = INFINITY; vmax[g] = -INFINITY; }

        bf16x8 jfr[4];
        #pragma unroll
        for (int ks = 0; ks < 4; ++ks) jfr[ks] = *(const bf16x8*)(jbase + ks * 32);

        #pragma unroll 1
        for (int jt = 0; jt < NJT; ++jt) {
            int4 lj = *(const int4*)(lbase + jt * JT);   // covered by MFMA block

            f32x4 acc[NG];
            #pragma unroll
            for (int g = 0; g < NG; ++g) acc[g] = (f32x4){0.f, 0.f, 0.f, 0.f};
            #pragma unroll
            for (int g = 0; g < NG; ++g)
                #pragma unroll
                for (int ks = 0; ks < 4; ++ks)
                    acc[g] = __builtin_amdgcn_mfma_f32_16x16x32_bf16(jfr[ks], ifr[g][ks], acc[g], 0, 0, 0);

            int nj = (jt + 1) & (NJT - 1);               // prefetch (epilogue covers)
            #pragma unroll
            for (int ks = 0; ks < 4; ++ks)
                jfr[ks] = *(const bf16x8*)(jbase + (size_t)nj * JT * DDIM + ks * 32);

            #pragma unroll
            for (int r = 0; r < 4; ++r) {
                int ljr = (r == 0) ? lj.x : (r == 1) ? lj.y : (r == 2) ? lj.z : lj.w;
                #pragma unroll
                for (int g = 0; g < NG; ++g) {
                    float s = acc[g][r];
                    bool same = (li[g] == ljr);
                    vmin[g] = fminf(vmin[g], same ? s : INFINITY);
                    vmax[g] = fmaxf(vmax[g], same ? -INFINITY : s);
                }
            }
        }

        #pragma unroll
        for (int g = 0; g < NG; ++g) {
            vmin[g] = fminf(vmin[g], __shfl_xor(vmin[g], 16, 64));
            vmin[g] = fminf(vmin[g], __shfl_xor(vmin[g], 32, 64));
            vmax[g] = fmaxf(vmax[g], __shfl_xor(vmax[g], 16, 64));
            vmax[g] = fmaxf(vmax[g], __shfl_xor(vmax[g], 32, 64));
        }
        if (q == 0) {
            #pragma unroll
            for (int g = 0; g < NG; ++g) {
                int row = iw0 + g * 16 + c;
                minp_part[by * B_N + row] = vmin[g];
                maxn_part[by * B_N + row] = vmax[g];
            }
        }
    }
    if (coop) { __threadfence(); cg::this_grid().sync(); }

    // ---------------- phase 2: fold partials -> bounds (LDS), then exp sums
    __shared__ float spb[128], snb[128];
    if (coop || phase == 2) {
        {
            int row = i0 + tid;
            float mn = INFINITY, mx = -INFINITY;
            #pragma unroll
            for (int s = 0; s < NSPLIT; ++s) {
                mn = fminf(mn, minp_part[s * B_N + row]);
                mx = fmaxf(mx, maxn_part[s * B_N + row]);
            }
            spb[tid] = fminf(ONE_EPS, mx + F_MARGIN);   // pos kept iff s < pb
            snb[tid] = mn - F_MARGIN;                   // neg kept iff s >= nb
        }
        __syncthreads();

        bf16x8 ifr[NG][4];
        int    li[NG];
        float  pb[NG], nb[NG], ps[NG], ns[NG];
        #pragma unroll
        for (int g = 0; g < NG; ++g) {
            int row = iw0 + g * 16 + c;
            #pragma unroll
            for (int ks = 0; ks < 4; ++ks)
                ifr[g][ks] = *(const bf16x8*)(fb + row * DDIM + ks * 32 + q * 8);
            li[g] = labels[row];
            pb[g] = spb[w * 64 + g * 16 + c];
            nb[g] = snb[w * 64 + g * 16 + c];
            ps[g] = 0.f; ns[g] = 0.f;
        }

        bf16x8 jfr[4];
        #pragma unroll
        for (int ks = 0; ks < 4; ++ks) jfr[ks] = *(const bf16x8*)(jbase + ks * 32);

        #pragma unroll 1
        for (int jt = 0; jt < NJT; ++jt) {
            int4 lj = *(const int4*)(lbase + jt * JT);

            f32x4 acc[NG];
            #pragma unroll
            for (int g = 0; g < NG; ++g) acc[g] = (f32x4){0.f, 0.f, 0.f, 0.f};
            #pragma unroll
            for (int g = 0; g < NG; ++g)
                #pragma unroll
                for (int ks = 0; ks < 4; ++ks)
                    acc[g] = __builtin_amdgcn_mfma_f32_16x16x32_bf16(jfr[ks], ifr[g][ks], acc[g], 0, 0, 0);

            int nj = (jt + 1) & (NJT - 1);
            #pragma unroll
            for (int ks = 0; ks < 4; ++ks)
                jfr[ks] = *(const bf16x8*)(jbase + (size_t)nj * JT * DDIM + ks * 32);

            #pragma unroll
            for (int r = 0; r < 4; ++r) {
                int ljr = (r == 0) ? lj.x : (r == 1) ? lj.y : (r == 2) ? lj.z : lj.w;
                #pragma unroll
                for (int g = 0; g < NG; ++g) {
                    float s = acc[g][r];
                    bool same = (li[g] == ljr);
                    float e = EXP2F(fmaf(s, same ? KP2A : KN2A, same ? KP2B : KN2B));
                    bool lt = s < (same ? pb[g] : nb[g]);
                    ps[g] += (same && lt)   ? e : 0.0f;   // pos: s < pb
                    ns[g] += (!same && !lt) ? e : 0.0f;   // neg: s >= nb
                }
            }
        }

        #pragma unroll
        for (int g = 0; g < NG; ++g) {
            ps[g] += __shfl_xor(ps[g], 16, 64);
            ps[g] += __shfl_xor(ps[g], 32, 64);
            ns[g] += __shfl_xor(ns[g], 16, 64);
            ns[g] += __shfl_xor(ns[g], 32, 64);
        }
        if (q == 0) {
            #pragma unroll
            for (int g = 0; g < NG; ++g) {
                int row = iw0 + g * 16 + c;
                psum_part[by * B_N + row] = ps[g];
                nsum_part[by * B_N + row] = ns[g];
            }
        }
    }
    if (coop) { __threadfence(); cg::this_grid().sync(); }

    // ---------------- phase 3: finalize (first NIB blocks; 1 row/thread)
    // validity ps>0 && ns>0 == ref's valid: kept terms >= ~1e-27, never 0;
    // nonempty stage-2 masks imply has_pos/has_neg.
    if ((coop || phase == 3) && bid < NIB) {
        int i = bid * 128 + tid;
        float ps = 0.f, ns = 0.f;
        #pragma unroll
        for (int s = 0; s < NSPLIT; ++s) {
            ps += psum_part[s * B_N + i];
            ns += nsum_part[s * B_N + i];
        }
        float rl = 0.f;
        if (ps > 0.f && ns > 0.f)
            rl = log1pf(ps) * 0.5f + log1pf(ns) * 0.025f;   // /SCALE_POS, /SCALE_NEG

        #pragma unroll
        for (int off = 32; off > 0; off >>= 1) rl += __shfl_down(rl, off, 64);
        __shared__ float wsum[2];
        int l = tid & 63, wv = tid >> 6;
        if (l == 0) wsum[wv] = rl;
        __syncthreads();
        if (tid == 0)
            atomicAdd(out, (wsum[0] + wsum[1]) * (1.0f / (float)B_N));
    }
}

// ---------------------------------------------------------------- launch
extern "C" void kernel_launch(void* const* d_in, const int* in_sizes, int n_in,
                              void* d_out, int out_size, void* d_ws, size_t ws_size,
                              hipStream_t stream)
{
    const float* feats  = (const float*)d_in[0];
    const int*   labels = (const int*)d_in[1];

    char*   wsb       = (char*)d_ws;
    ushort* fb        = (ushort*)wsb;                          // 8192*128 bf16 = 2 MB
    float*  minp_part = (float*)(wsb + (size_t)2 * 1024 * 1024);
    float*  maxn_part = minp_part + (size_t)NSPLIT * B_N;      // 512 KB each
    float*  psum_part = maxn_part + (size_t)NSPLIT * B_N;
    float*  nsum_part = psum_part + (size_t)NSPLIT * B_N;
    float*  outp      = (float*)d_out;

    hipMemsetAsync(d_out, 0, sizeof(float), stream);

    int ph = -1;
    void* args[] = { (void*)&ph, (void*)&feats, (void*)&labels, (void*)&fb,
                     (void*)&minp_part, (void*)&maxn_part,
                     (void*)&psum_part, (void*)&nsum_part, (void*)&outp };
    hipError_t e = hipLaunchCooperativeKernel((const void*)ms_all,
                                              dim3(NSPLIT * NIB), dim3(128),
                                              args, 0, stream);
    if (e != hipSuccess) {
        (void)hipGetLastError();   // clear sticky error, use phase-sliced path
        for (int p = 0; p < 4; ++p)
            ms_all<<<dim3(NSPLIT * NIB), dim3(128), 0, stream>>>(
                p, feats, labels, fb, minp_part, maxn_part,
                psum_part, nsum_part, outp);
    }
}

// Round 9
// 244.891 us; speedup vs baseline: 2.1308x; 2.1308x over previous
//
#include <hip/hip_runtime.h>
#include <hip/hip_bf16.h>
#include <math.h>

// MultiSimilarityLoss B=8192 D=128, sim = F·F^T via bf16 MFMA 16x16x32.
// R9: 3-node graph (cast | ms1 | ms2+finalize). Cooperative grid.sync is
// unusable (R8: 3 syncs cost ~440us, VALUBusy 6.8%). Finalize is fused into
// ms2 via device-scope last-block counters (zeroed by the cast dispatch);
// out is plain-stored by the globally-last block (no d_out memset node).
// Phase bodies: streamed j = A operand, persistent i = B operand (D col = i);
// batched 16-MFMA block -> jfr prefetch -> single epilogue (R8: VGPR=64,
// no spill); native v_exp2 with base-2-folded constants.

#define B_N    8192
#define DDIM   128
#define NSPLIT 32               // j-splits
#define NIB    32               // i-blocks; grid = 32x32 = 1024, 256 thr
#define JRANGE 256              // j per block
#define JT     16               // j rows per MFMA tile
#define NJT    16               // j-tiles per block
#define NG     4                // 16-i groups per wave (64 i per wave)

typedef __attribute__((ext_vector_type(8))) short bf16x8;  // 8 bf16 = 4 VGPRs
typedef __attribute__((ext_vector_type(4))) float f32x4;

static constexpr float ONE_EPS  = 1.0f - 1e-5f;
static constexpr float F_MARGIN = 0.1f;
// base-2 folded: exp(-2(s-.5)) = 2^(KP2A*s+KP2B) ; exp(40(s-.5)) = 2^(KN2A*s+KN2B)
static constexpr float KP2A = -2.8853900817779268f, KP2B =  1.4426950408889634f;
static constexpr float KN2A = 57.7078016355585400f, KN2B = -28.8539008177792680f;

#if __has_builtin(__builtin_amdgcn_exp2f)
#define EXP2F(x) __builtin_amdgcn_exp2f(x)
#else
#define EXP2F(x) __expf((x) * 0.6931471805599453f)
#endif

// ---------------------------------------------------------------- cast + counter zero
__global__ __launch_bounds__(256)
void ms_cast(const float* __restrict__ f, ushort* __restrict__ fb,
             int* __restrict__ counters)
{
    if (blockIdx.x == 0 && threadIdx.x <= NIB) counters[threadIdx.x] = 0;
    int i = (blockIdx.x * 256 + threadIdx.x) * 4;
    float4 v = *(const float4*)(f + i);
    ushort4 o; uint u;
    u = __float_as_uint(v.x); o.x = (ushort)((u + 0x7fffu + ((u >> 16) & 1u)) >> 16);
    u = __float_as_uint(v.y); o.y = (ushort)((u + 0x7fffu + ((u >> 16) & 1u)) >> 16);
    u = __float_as_uint(v.z); o.z = (ushort)((u + 0x7fffu + ((u >> 16) & 1u)) >> 16);
    u = __float_as_uint(v.w); o.w = (ushort)((u + 0x7fffu + ((u >> 16) & 1u)) >> 16);
    *(ushort4*)(fb + i) = o;
}

// ---------------------------------------------------------------- stage 1: min_pos / max_neg
__global__ __launch_bounds__(256, 4)
void ms1(const ushort* __restrict__ fb, const int* __restrict__ labels,
         float* __restrict__ minp_part, float* __restrict__ maxn_part)
{
    const int tid = threadIdx.x;
    const int bx  = blockIdx.x, by = blockIdx.y;
    const int w   = tid >> 6, lane = tid & 63;
    const int q   = lane >> 4, c = lane & 15;
    const int i0  = bx * 256, j0 = by * JRANGE;
    const int iw0 = i0 + w * 64;

    bf16x8 ifr[NG][4];                 // persistent i-side (B operand)
    int    li[NG];
    #pragma unroll
    for (int g = 0; g < NG; ++g) {
        int row = iw0 + g * 16 + c;
        #pragma unroll
        for (int ks = 0; ks < 4; ++ks)
            ifr[g][ks] = *(const bf16x8*)(fb + row * DDIM + ks * 32 + q * 8);
        li[g] = labels[row];
    }

    float vmin[NG], vmax[NG];
    #pragma unroll
    for (int g = 0; g < NG; ++g) { vmin[g] = INFINITY; vmax[g] = -INFINITY; }

    const ushort* jbase = fb + (size_t)(j0 + c) * DDIM + q * 8;
    const int*    lbase = labels + j0 + q * 4;

    bf16x8 jfr[4];
    #pragma unroll
    for (int ks = 0; ks < 4; ++ks) jfr[ks] = *(const bf16x8*)(jbase + ks * 32);

    #pragma unroll 1
    for (int jt = 0; jt < NJT; ++jt) {
        int4 lj = *(const int4*)(lbase + jt * JT);   // covered by MFMA block

        f32x4 acc[NG];
        #pragma unroll
        for (int g = 0; g < NG; ++g) acc[g] = (f32x4){0.f, 0.f, 0.f, 0.f};
        #pragma unroll
        for (int g = 0; g < NG; ++g)
            #pragma unroll
            for (int ks = 0; ks < 4; ++ks)
                acc[g] = __builtin_amdgcn_mfma_f32_16x16x32_bf16(jfr[ks], ifr[g][ks], acc[g], 0, 0, 0);

        int nj = (jt + 1) & (NJT - 1);               // prefetch (epilogue covers)
        #pragma unroll
        for (int ks = 0; ks < 4; ++ks)
            jfr[ks] = *(const bf16x8*)(jbase + (size_t)nj * JT * DDIM + ks * 32);

        #pragma unroll
        for (int r = 0; r < 4; ++r) {
            int ljr = (r == 0) ? lj.x : (r == 1) ? lj.y : (r == 2) ? lj.z : lj.w;
            #pragma unroll
            for (int g = 0; g < NG; ++g) {
                float s = acc[g][r];
                bool same = (li[g] == ljr);
                vmin[g] = fminf(vmin[g], same ? s : INFINITY);
                vmax[g] = fmaxf(vmax[g], same ? -INFINITY : s);
            }
        }
    }

    #pragma unroll
    for (int g = 0; g < NG; ++g) {
        vmin[g] = fminf(vmin[g], __shfl_xor(vmin[g], 16, 64));
        vmin[g] = fminf(vmin[g], __shfl_xor(vmin[g], 32, 64));
        vmax[g] = fmaxf(vmax[g], __shfl_xor(vmax[g], 16, 64));
        vmax[g] = fmaxf(vmax[g], __shfl_xor(vmax[g], 32, 64));
    }
    if (q == 0) {
        #pragma unroll
        for (int g = 0; g < NG; ++g) {
            int row = iw0 + g * 16 + c;
            minp_part[by * B_N + row] = vmin[g];
            maxn_part[by * B_N + row] = vmax[g];
        }
    }
}

// ---------------------------------------------------------------- stage 2 + finalize
__global__ __launch_bounds__(256, 4)
void ms2(const ushort* __restrict__ fb, const int* __restrict__ labels,
         const float* __restrict__ minp_part, const float* __restrict__ maxn_part,
         float* __restrict__ psum_part, float* __restrict__ nsum_part,
         float* __restrict__ slot, int* __restrict__ counters,
         float* __restrict__ out)
{
    const int tid = threadIdx.x;
    const int bx  = blockIdx.x, by = blockIdx.y;
    const int w   = tid >> 6, lane = tid & 63;
    const int q   = lane >> 4, c = lane & 15;
    const int i0  = bx * 256, j0 = by * JRANGE;
    const int iw0 = i0 + w * 64;

    // fold stage-1 partials -> per-row bounds:
    //   pb = min(1-eps, max_neg + margin)  (pos kept iff s < pb)
    //   nb = min_pos - margin              (neg kept iff s >= nb)
    __shared__ float spb[256], snb[256];
    {
        int row = i0 + tid;
        float mn = INFINITY, mx = -INFINITY;
        #pragma unroll
        for (int s = 0; s < NSPLIT; ++s) {
            mn = fminf(mn, minp_part[s * B_N + row]);
            mx = fmaxf(mx, maxn_part[s * B_N + row]);
        }
        spb[tid] = fminf(ONE_EPS, mx + F_MARGIN);
        snb[tid] = mn - F_MARGIN;
    }
    __syncthreads();

    bf16x8 ifr[NG][4];
    int    li[NG];
    float  pb[NG], nb[NG], ps[NG], ns[NG];
    #pragma unroll
    for (int g = 0; g < NG; ++g) {
        int row = iw0 + g * 16 + c;
        #pragma unroll
        for (int ks = 0; ks < 4; ++ks)
            ifr[g][ks] = *(const bf16x8*)(fb + row * DDIM + ks * 32 + q * 8);
        li[g] = labels[row];
        pb[g] = spb[w * 64 + g * 16 + c];
        nb[g] = snb[w * 64 + g * 16 + c];
        ps[g] = 0.f; ns[g] = 0.f;
    }

    const ushort* jbase = fb + (size_t)(j0 + c) * DDIM + q * 8;
    const int*    lbase = labels + j0 + q * 4;

    bf16x8 jfr[4];
    #pragma unroll
    for (int ks = 0; ks < 4; ++ks) jfr[ks] = *(const bf16x8*)(jbase + ks * 32);

    #pragma unroll 1
    for (int jt = 0; jt < NJT; ++jt) {
        int4 lj = *(const int4*)(lbase + jt * JT);

        f32x4 acc[NG];
        #pragma unroll
        for (int g = 0; g < NG; ++g) acc[g] = (f32x4){0.f, 0.f, 0.f, 0.f};
        #pragma unroll
        for (int g = 0; g < NG; ++g)
            #pragma unroll
            for (int ks = 0; ks < 4; ++ks)
                acc[g] = __builtin_amdgcn_mfma_f32_16x16x32_bf16(jfr[ks], ifr[g][ks], acc[g], 0, 0, 0);

        int nj = (jt + 1) & (NJT - 1);
        #pragma unroll
        for (int ks = 0; ks < 4; ++ks)
            jfr[ks] = *(const bf16x8*)(jbase + (size_t)nj * JT * DDIM + ks * 32);

        #pragma unroll
        for (int r = 0; r < 4; ++r) {
            int ljr = (r == 0) ? lj.x : (r == 1) ? lj.y : (r == 2) ? lj.z : lj.w;
            #pragma unroll
            for (int g = 0; g < NG; ++g) {
                float s = acc[g][r];
                bool same = (li[g] == ljr);
                float e = EXP2F(fmaf(s, same ? KP2A : KN2A, same ? KP2B : KN2B));
                bool lt = s < (same ? pb[g] : nb[g]);
                ps[g] += (same && lt)   ? e : 0.0f;   // pos: s < pb
                ns[g] += (!same && !lt) ? e : 0.0f;   // neg: s >= nb
            }
        }
    }

    #pragma unroll
    for (int g = 0; g < NG; ++g) {
        ps[g] += __shfl_xor(ps[g], 16, 64);
        ps[g] += __shfl_xor(ps[g], 32, 64);
        ns[g] += __shfl_xor(ns[g], 16, 64);
        ns[g] += __shfl_xor(ns[g], 32, 64);
    }
    if (q == 0) {
        #pragma unroll
        for (int g = 0; g < NG; ++g) {
            int row = iw0 + g * 16 + c;
            psum_part[by * B_N + row] = ps[g];
            nsum_part[by * B_N + row] = ns[g];
        }
    }

    // -------- last block per i-range finalizes its 256 rows ----------------
    __threadfence();                                  // release partials
    __shared__ int lastFlag;
    if (tid == 0) lastFlag = (atomicAdd(&counters[bx], 1) == NSPLIT - 1);
    __syncthreads();
    if (!lastFlag) return;
    __threadfence();                                  // acquire others' partials

    {
        int row = i0 + tid;
        float fps = 0.f, fns = 0.f;
        #pragma unroll
        for (int s = 0; s < NSPLIT; ++s) {
            fps += psum_part[s * B_N + row];
            fns += nsum_part[s * B_N + row];
        }
        // validity fps>0 && fns>0 == ref's valid: kept terms >= ~1e-27,
        // never flush to 0; nonempty stage-2 masks imply has_pos/has_neg.
        float rl = 0.f;
        if (fps > 0.f && fns > 0.f)
            rl = log1pf(fps) * 0.5f + log1pf(fns) * 0.025f;

        #pragma unroll
        for (int off = 32; off > 0; off >>= 1) rl += __shfl_down(rl, off, 64);
        __shared__ float wsum[4];
        if (lane == 0) wsum[w] = rl;
        __syncthreads();
        if (tid == 0) {
            slot[bx] = wsum[0] + wsum[1] + wsum[2] + wsum[3];
            __threadfence();
            // globally-last block sums the 32 slots, stores out (no memset)
            if (atomicAdd(&counters[NIB], 1) == NIB - 1) {
                __threadfence();
                float t = 0.f;
                #pragma unroll
                for (int k = 0; k < NIB; ++k) t += slot[k];
                out[0] = t * (1.0f / (float)B_N);
            }
        }
    }
}

// ---------------------------------------------------------------- launch
extern "C" void kernel_launch(void* const* d_in, const int* in_sizes, int n_in,
                              void* d_out, int out_size, void* d_ws, size_t ws_size,
                              hipStream_t stream)
{
    const float* feats  = (const float*)d_in[0];
    const int*   labels = (const int*)d_in[1];

    char*   wsb       = (char*)d_ws;
    ushort* fb        = (ushort*)wsb;                          // 2 MB
    float*  minp_part = (float*)(wsb + (size_t)2 * 1024 * 1024);
    float*  maxn_part = minp_part + (size_t)NSPLIT * B_N;      // 1 MB each
    float*  psum_part = maxn_part + (size_t)NSPLIT * B_N;
    float*  nsum_part = psum_part + (size_t)NSPLIT * B_N;
    float*  slot      = nsum_part + (size_t)NSPLIT * B_N;      // 32 floats
    int*    counters  = (int*)(slot + NIB);                    // NIB+1 ints

    ms_cast<<<(B_N * DDIM) / (256 * 4), 256, 0, stream>>>(feats, fb, counters);
    ms1<<<dim3(NIB, NSPLIT), 256, 0, stream>>>(fb, labels, minp_part, maxn_part);
    ms2<<<dim3(NIB, NSPLIT), 256, 0, stream>>>(fb, labels, minp_part, maxn_part,
                                               psum_part, nsum_part,
                                               slot, counters, (float*)d_out);
}